// Round 17
// baseline (415.701 us; speedup 1.0000x reference)
//
#include <hip/hip_runtime.h>

#define NN 100000
#define NE 1200000
#define NG 2048
#define VOCAB 10000
#define D 64
#define C 2

#define NBK 196      // coarse buckets of 512 nodes (dst >> 9)
#define BSH 9
#define SLOT 7168    // per-bucket slot stride; mean 6144, sd 78 -> +13 sigma

__device__ __forceinline__ int atomAddI(int* p, int v) {
    return __hip_atomic_fetch_add(p, v, __ATOMIC_RELAXED, __HIP_MEMORY_SCOPE_AGENT);
}
__device__ __forceinline__ void atomAddF(float* p, float v) {
    __hip_atomic_fetch_add(p, v, __ATOMIC_RELAXED, __HIP_MEMORY_SCOPE_AGENT);
}

// ---------------- phase A: coarse bucket scatter (packed src|dlow) ----------------
__global__ void __launch_bounds__(256) k_bucket(const int* __restrict__ src,
        const int* __restrict__ dst, int* __restrict__ bcur, unsigned* __restrict__ barr) {
    __shared__ int hcnt[NBK], hbase[NBK], hrank[NBK];
    int tid = threadIdx.x;
    if (tid < NBK) { hcnt[tid] = 0; hrank[tid] = 0; }
    __syncthreads();
    int per = (NE + gridDim.x - 1) / gridDim.x;
    int e0 = blockIdx.x * per, e1 = min(e0 + per, NE);
    for (int e = e0 + tid; e < e1; e += 256)
        atomicAdd(&hcnt[dst[e] >> BSH], 1);
    __syncthreads();
    if (tid < NBK) {
        int c = hcnt[tid];
        hbase[tid] = c ? atomAddI(&bcur[tid], c) : 0;
    }
    __syncthreads();
    for (int e = e0 + tid; e < e1; e += 256) {
        int d = dst[e], s = src[e];
        int b = d >> BSH;
        int r = atomicAdd(&hrank[b], 1);
        barr[(size_t)b * SLOT + hbase[b] + r] = ((unsigned)s << BSH) | (unsigned)(d & 511);
    }
}

// ---------------- bucket-count scan ----------------
__global__ void __launch_bounds__(256) k_bscan(const int* __restrict__ bcur,
        int* __restrict__ bstart, int* __restrict__ start) {
    __shared__ int sm[256];
    int t = threadIdx.x;
    int v0 = (t < NBK) ? bcur[t] : 0;
    sm[t] = v0;
    __syncthreads();
    for (int off = 1; off < 256; off <<= 1) {
        int v = (t >= off) ? sm[t - off] : 0;
        __syncthreads();
        sm[t] += v;
        __syncthreads();
    }
    if (t < NBK) bstart[t] = sm[t] - v0;
    if (t == 0) { bstart[NBK] = NE; start[NN] = NE; }
}

// ---------------- phase B: exact CSR within each bucket ----------------
__global__ void __launch_bounds__(256) k_sortb(const int* __restrict__ bcur,
        const int* __restrict__ bstart, const unsigned* __restrict__ barr,
        int* __restrict__ start, int* __restrict__ csr) {
    __shared__ int cnt[512], loc[512], sm[256];
    int t = threadIdx.x;
    int b = blockIdx.x;
    cnt[t] = 0; cnt[t + 256] = 0;
    __syncthreads();
    int count = bcur[b];
    int base  = bstart[b];
    const unsigned* bp = barr + (size_t)b * SLOT;
    for (int i = t; i < count; i += 256)
        atomicAdd(&cnt[bp[i] & 511], 1);
    __syncthreads();
    int c0 = cnt[2 * t], c1 = cnt[2 * t + 1];
    int s = c0 + c1;
    sm[t] = s;
    __syncthreads();
    for (int off = 1; off < 256; off <<= 1) {
        int v = (t >= off) ? sm[t - off] : 0;
        __syncthreads();
        sm[t] += v;
        __syncthreads();
    }
    int ex = sm[t] - s;
    loc[2 * t] = ex; loc[2 * t + 1] = ex + c0;
    int g0 = b << BSH;
    if (g0 + 2 * t < NN)     start[g0 + 2 * t]     = base + ex;
    if (g0 + 2 * t + 1 < NN) start[g0 + 2 * t + 1] = base + ex + c0;
    __syncthreads();
    for (int i = t; i < count; i += 256) {
        unsigned p = bp[i];
        int r = atomicAdd(&loc[p & 511], 1);
        csr[base + r] = (int)(p >> BSH);
    }
}

// ---------------- embedding -> h0 slabs T0[c][n][8] ----------------
__global__ void __launch_bounds__(256) k_embedT(const int* __restrict__ x, const float* __restrict__ emb,
                         float* __restrict__ T0) {
    int tid = blockIdx.x * blockDim.x + threadIdx.x;
    if (tid >= NN * 64) return;
    int c = tid / (NN * 8);
    int r = tid % (NN * 8);
    int n = r >> 3, f = r & 7;
    T0[tid] = emb[(size_t)x[n] * 64 + c * 8 + f];
}

// ---------------- chunked aggregate: float2 lanes (16 edges / gather instr) ----
__global__ void __launch_bounds__(256) k_agg2(const int* __restrict__ start,
        const int* __restrict__ csr, const float* __restrict__ gT,
        float* __restrict__ aggT) {
    int tid = threadIdx.x;
    int lane = tid & 63, wave = tid >> 6;
    int c  = blockIdx.x & 7;
    int nb = blockIdx.x >> 3;            // 0..781
    int f2 = lane & 3, nsub = lane >> 2; // nsub 0..15
    const float2* gsl2 = (const float2*)(gT + (size_t)c * NN * 8);
    float2* asl2 = (float2*)(aggT + (size_t)c * NN * 8);

    // streaming L2 warm of this block's slab slice
    float pf = 0.f;
    {
        int i = nb * 256 + tid;
        if (i < NN * 2) {
            float4 v = ((const float4*)gsl2)[i];
            pf = v.x * 0.0f;
        }
    }

    int nbase = nb * 128 + wave * 16 + nsub;
    for (int b = 0; b < 2; ++b) {
        int n = nbase + b * 64;
        if (n >= NN) break;
        int s0 = start[n], s1 = start[n + 1];
        float inv = 1.0f / (float)max(s1 - s0, 1);
        float ax = pf, ay = 0.f, bx = 0.f, by = 0.f;
        int i = s0;
        for (; i + 4 <= s1; i += 4) {
            int c0 = csr[i], c1 = csr[i + 1], c2 = csr[i + 2], c3 = csr[i + 3];
            float2 v0 = gsl2[(size_t)c0 * 4 + f2];
            float2 v1 = gsl2[(size_t)c1 * 4 + f2];
            float2 v2 = gsl2[(size_t)c2 * 4 + f2];
            float2 v3 = gsl2[(size_t)c3 * 4 + f2];
            ax += v0.x + v1.x; ay += v0.y + v1.y;
            bx += v2.x + v3.x; by += v2.y + v3.y;
        }
        for (; i < s1; ++i) {
            float2 v = gsl2[(size_t)csr[i] * 4 + f2];
            ax += v.x; ay += v.y;
        }
        float2 o;
        o.x = (ax + bx) * inv;
        o.y = (ay + by) * inv;
        asl2[(size_t)n * 4 + f2] = o;
    }
}

// ---------------- SAGE linear (+ReLU): one THREAD per node ----------------
// __launch_bounds__(256, 2): VGPR budget 256/wave so acc[64] + pipelined inputs
// stay in registers (default bounds capped at ~64 VGPR -> scratch spill, R16).
__global__ void __launch_bounds__(256, 2) k_lin3(const float* __restrict__ aggT,
        const float* __restrict__ rootT,
        const float* __restrict__ Wl, const float* __restrict__ bl,
        const float* __restrict__ Wr, float* __restrict__ outT) {
    int tid = blockIdx.x * 256 + threadIdx.x;
    int n = tid < NN ? tid : NN - 1;   // clamp; store guarded

    float acc[64];
#pragma unroll
    for (int d = 0; d < 64; ++d) acc[d] = bl[d];

    const float4* ap = (const float4*)(aggT + (size_t)n * 8);
    const float4* rp = (const float4*)(rootT + (size_t)n * 8);
    const size_t cstep = (size_t)NN * 2;   // chunk stride in float4s

    float4 a0 = ap[0], a1 = ap[1], r0 = rp[0], r1 = rp[1];
    for (int c = 0; c < 8; ++c) {
        float av[8] = {a0.x, a0.y, a0.z, a0.w, a1.x, a1.y, a1.z, a1.w};
        float rv[8] = {r0.x, r0.y, r0.z, r0.w, r1.x, r1.y, r1.z, r1.w};
        if (c < 7) {
            size_t off = (size_t)(c + 1) * cstep;
            a0 = ap[off]; a1 = ap[off + 1];
            r0 = rp[off]; r1 = rp[off + 1];
        }
        const float* wlc = Wl + c * 8;   // row d, cols c*8..c*8+7
        const float* wrc = Wr + c * 8;
#pragma unroll
        for (int d = 0; d < 64; ++d) {
#pragma unroll
            for (int k = 0; k < 8; ++k) {
                acc[d] += av[k] * wlc[d * 64 + k];
                acc[d] += rv[k] * wrc[d * 64 + k];
            }
        }
    }

    if (tid < NN) {
#pragma unroll
        for (int c = 0; c < 8; ++c) {
            float4 o0, o1;
            o0.x = fmaxf(acc[c * 8 + 0], 0.f); o0.y = fmaxf(acc[c * 8 + 1], 0.f);
            o0.z = fmaxf(acc[c * 8 + 2], 0.f); o0.w = fmaxf(acc[c * 8 + 3], 0.f);
            o1.x = fmaxf(acc[c * 8 + 4], 0.f); o1.y = fmaxf(acc[c * 8 + 5], 0.f);
            o1.z = fmaxf(acc[c * 8 + 6], 0.f); o1.w = fmaxf(acc[c * 8 + 7], 0.f);
            float4* op = (float4*)(outT + (size_t)c * NN * 8 + (size_t)n * 8);
            op[0] = o0; op[1] = o1;
        }
    }
}

// ---------------- per-graph mean-pool from h2 slabs (batch sorted) ----------------
__global__ void __launch_bounds__(256) k_pools(const float* __restrict__ hT,
        const int* __restrict__ batch, float* __restrict__ pooled) {
    int lane = threadIdx.x & 63;
    int wave = threadIdx.x >> 6;
    int n0 = blockIdx.x * 256 + wave * 64;
    if (n0 >= NN) return;
    const float* base = hT + (size_t)(lane >> 3) * NN * 8 + (lane & 7);
    int gcur = batch[n0];
    float rsum = 0.f;
    int nend = min(n0 + 64, NN);
    for (int n = n0; n < nend; ++n) {
        float v = base[(size_t)n * 8];
        int g = batch[n];
        if (g != gcur) {
            atomAddF(&pooled[(size_t)gcur * D + lane], rsum);
            rsum = 0.f; gcur = g;
        }
        rsum += v;
    }
    atomAddF(&pooled[(size_t)gcur * D + lane], rsum);
}

// ---------------- readout ----------------
__global__ void __launch_bounds__(256) k_bounds(const int* __restrict__ batch, int* __restrict__ gs) {
    int n = blockIdx.x * blockDim.x + threadIdx.x;
    if (n >= NN) return;
    int b = batch[n];
    if (n == 0) {
        for (int g = 0; g <= b; ++g) gs[g] = 0;
    } else {
        int bp = batch[n - 1];
        for (int g = bp + 1; g <= b; ++g) gs[g] = n;
    }
    if (n == NN - 1) {
        for (int g = b + 1; g <= NG; ++g) gs[g] = NN;
    }
}

__global__ void __launch_bounds__(256) k_out(const int* __restrict__ gs,
        const float* __restrict__ pooled, const float* __restrict__ Wout,
        const float* __restrict__ bout, float* __restrict__ out) {
    int lane = threadIdx.x & 63;
    int wave = threadIdx.x >> 6;
    int g = blockIdx.x * 4 + wave;       // 512 blocks
    int s0 = gs[g], s1 = gs[g + 1];
    float p = pooled[(size_t)g * D + lane] / (float)max(s1 - s0, 1);
    float c0 = p * Wout[lane];
    float c1 = p * Wout[D + lane];
#pragma unroll
    for (int off = 32; off > 0; off >>= 1) {
        c0 += __shfl_down(c0, off, 64);
        c1 += __shfl_down(c1, off, 64);
    }
    if (lane == 0) {
        out[g * C + 0] = c0 + bout[0];
        out[g * C + 1] = c1 + bout[1];
    }
}

extern "C" void kernel_launch(void* const* d_in, const int* in_sizes, int n_in,
                              void* d_out, int out_size, void* d_ws, size_t ws_size,
                              hipStream_t stream) {
    const int*   x     = (const int*)d_in[0];
    const int*   src   = (const int*)d_in[1];
    const int*   dst   = src + NE;
    const int*   batch = (const int*)d_in[2];
    const float* emb   = (const float*)d_in[3];
    const float* W1l   = (const float*)d_in[4];
    const float* b1l   = (const float*)d_in[5];
    const float* W1r   = (const float*)d_in[6];
    const float* W2l   = (const float*)d_in[7];
    const float* b2l   = (const float*)d_in[8];
    const float* W2r   = (const float*)d_in[9];
    const float* Wout  = (const float*)d_in[10];
    const float* bout  = (const float*)d_in[11];
    float* out = (float*)d_out;

    float* T0     = (float*)d_ws;                 // NN*64  h0 -> h1 slabs (in place)
    float* TA     = T0 + (size_t)NN * 64;         // NN*64  agg slabs -> h2 slabs (in place)
    float* pooled = TA + (size_t)NN * 64;         // NG*64
    int* bcur   = (int*)(pooled + (size_t)NG * 64);  // NBK  (contiguous w/ pooled for memset)
    int* bstart = bcur + NBK;                        // NBK+1
    int* startA = bstart + NBK + 1;                  // NN+1
    int* gs     = startA + NN + 1;                   // NG+1
    int* csr    = gs + NG + 1;                       // NE
    unsigned* barr = (unsigned*)(csr + NE);          // NBK*SLOT (~5.6 MB)

    hipMemsetAsync(pooled, 0, ((size_t)NG * 64 + NBK) * sizeof(float), stream);

    k_bucket<<<192, 256, 0, stream>>>(src, dst, bcur, barr);
    k_bscan <<<1, 256, 0, stream>>>(bcur, bstart, startA);
    k_sortb <<<NBK, 256, 0, stream>>>(bcur, bstart, barr, startA, csr);
    k_bounds<<<(NN + 255) / 256, 256, 0, stream>>>(batch, gs);
    k_embedT<<<(NN * 64 + 255) / 256, 256, 0, stream>>>(x, emb, T0);

    // ---- layer 1 ----
    k_agg2<<<((NN + 127) / 128) * 8, 256, 0, stream>>>(startA, csr, T0, TA);
    k_lin3<<<(NN + 255) / 256, 256, 0, stream>>>(TA, T0, W1l, b1l, W1r, T0);
    // ---- layer 2 ----
    k_agg2<<<((NN + 127) / 128) * 8, 256, 0, stream>>>(startA, csr, T0, TA);
    k_lin3<<<(NN + 255) / 256, 256, 0, stream>>>(TA, T0, W2l, b2l, W2r, TA);

    // ---- readout ----
    k_pools<<<(NN + 255) / 256, 256, 0, stream>>>(TA, batch, pooled);
    k_out<<<NG / 4, 256, 0, stream>>>(gs, pooled, Wout, bout, out);
}

// Round 18
// 373.235 us; speedup vs baseline: 1.1138x; 1.1138x over previous
//
#include <hip/hip_runtime.h>

#define NN 100000
#define NE 1200000
#define NG 2048
#define VOCAB 10000
#define D 64
#define C 2

#define NBK 196      // coarse buckets of 512 nodes (dst >> 9)
#define BSH 9
#define SLOT 7168    // per-bucket slot stride; mean 6144, sd 78 -> +13 sigma

__device__ __forceinline__ int atomAddI(int* p, int v) {
    return __hip_atomic_fetch_add(p, v, __ATOMIC_RELAXED, __HIP_MEMORY_SCOPE_AGENT);
}
__device__ __forceinline__ void atomAddF(float* p, float v) {
    __hip_atomic_fetch_add(p, v, __ATOMIC_RELAXED, __HIP_MEMORY_SCOPE_AGENT);
}

// ---------------- phase A: coarse bucket scatter (packed src|dlow) ----------------
__global__ void __launch_bounds__(256) k_bucket(const int* __restrict__ src,
        const int* __restrict__ dst, int* __restrict__ bcur, unsigned* __restrict__ barr) {
    __shared__ int hcnt[NBK], hbase[NBK], hrank[NBK];
    int tid = threadIdx.x;
    if (tid < NBK) { hcnt[tid] = 0; hrank[tid] = 0; }
    __syncthreads();
    int per = (NE + gridDim.x - 1) / gridDim.x;
    int e0 = blockIdx.x * per, e1 = min(e0 + per, NE);
    for (int e = e0 + tid; e < e1; e += 256)
        atomicAdd(&hcnt[dst[e] >> BSH], 1);
    __syncthreads();
    if (tid < NBK) {
        int c = hcnt[tid];
        hbase[tid] = c ? atomAddI(&bcur[tid], c) : 0;
    }
    __syncthreads();
    for (int e = e0 + tid; e < e1; e += 256) {
        int d = dst[e], s = src[e];
        int b = d >> BSH;
        int r = atomicAdd(&hrank[b], 1);
        barr[(size_t)b * SLOT + hbase[b] + r] = ((unsigned)s << BSH) | (unsigned)(d & 511);
    }
}

// ---------------- bucket-count scan ----------------
__global__ void __launch_bounds__(256) k_bscan(const int* __restrict__ bcur,
        int* __restrict__ bstart, int* __restrict__ start) {
    __shared__ int sm[256];
    int t = threadIdx.x;
    int v0 = (t < NBK) ? bcur[t] : 0;
    sm[t] = v0;
    __syncthreads();
    for (int off = 1; off < 256; off <<= 1) {
        int v = (t >= off) ? sm[t - off] : 0;
        __syncthreads();
        sm[t] += v;
        __syncthreads();
    }
    if (t < NBK) bstart[t] = sm[t] - v0;
    if (t == 0) { bstart[NBK] = NE; start[NN] = NE; }
}

// ---------------- phase B: exact CSR within each bucket ----------------
__global__ void __launch_bounds__(256) k_sortb(const int* __restrict__ bcur,
        const int* __restrict__ bstart, const unsigned* __restrict__ barr,
        int* __restrict__ start, int* __restrict__ csr) {
    __shared__ int cnt[512], loc[512], sm[256];
    int t = threadIdx.x;
    int b = blockIdx.x;
    cnt[t] = 0; cnt[t + 256] = 0;
    __syncthreads();
    int count = bcur[b];
    int base  = bstart[b];
    const unsigned* bp = barr + (size_t)b * SLOT;
    for (int i = t; i < count; i += 256)
        atomicAdd(&cnt[bp[i] & 511], 1);
    __syncthreads();
    int c0 = cnt[2 * t], c1 = cnt[2 * t + 1];
    int s = c0 + c1;
    sm[t] = s;
    __syncthreads();
    for (int off = 1; off < 256; off <<= 1) {
        int v = (t >= off) ? sm[t - off] : 0;
        __syncthreads();
        sm[t] += v;
        __syncthreads();
    }
    int ex = sm[t] - s;
    loc[2 * t] = ex; loc[2 * t + 1] = ex + c0;
    int g0 = b << BSH;
    if (g0 + 2 * t < NN)     start[g0 + 2 * t]     = base + ex;
    if (g0 + 2 * t + 1 < NN) start[g0 + 2 * t + 1] = base + ex + c0;
    __syncthreads();
    for (int i = t; i < count; i += 256) {
        unsigned p = bp[i];
        int r = atomicAdd(&loc[p & 511], 1);
        csr[base + r] = (int)(p >> BSH);
    }
}

// ---------------- embedding -> h0 slabs T0[c][n][8] ----------------
__global__ void __launch_bounds__(256) k_embedT(const int* __restrict__ x, const float* __restrict__ emb,
                         float* __restrict__ T0) {
    int tid = blockIdx.x * blockDim.x + threadIdx.x;
    if (tid >= NN * 64) return;
    int c = tid / (NN * 8);
    int r = tid % (NN * 8);
    int n = r >> 3, f = r & 7;
    T0[tid] = emb[(size_t)x[n] * 64 + c * 8 + f];
}

// ---------------- chunked aggregate: float2 lanes (16 edges / gather instr) ----
__global__ void __launch_bounds__(256) k_agg2(const int* __restrict__ start,
        const int* __restrict__ csr, const float* __restrict__ gT,
        float* __restrict__ aggT) {
    int tid = threadIdx.x;
    int lane = tid & 63, wave = tid >> 6;
    int c  = blockIdx.x & 7;
    int nb = blockIdx.x >> 3;            // 0..781
    int f2 = lane & 3, nsub = lane >> 2; // nsub 0..15
    const float2* gsl2 = (const float2*)(gT + (size_t)c * NN * 8);
    float2* asl2 = (float2*)(aggT + (size_t)c * NN * 8);

    // streaming L2 warm of this block's slab slice
    float pf = 0.f;
    {
        int i = nb * 256 + tid;
        if (i < NN * 2) {
            float4 v = ((const float4*)gsl2)[i];
            pf = v.x * 0.0f;
        }
    }

    int nbase = nb * 128 + wave * 16 + nsub;
    for (int b = 0; b < 2; ++b) {
        int n = nbase + b * 64;
        if (n >= NN) break;
        int s0 = start[n], s1 = start[n + 1];
        float inv = 1.0f / (float)max(s1 - s0, 1);
        float ax = pf, ay = 0.f, bx = 0.f, by = 0.f;
        int i = s0;
        for (; i + 4 <= s1; i += 4) {
            int c0 = csr[i], c1 = csr[i + 1], c2 = csr[i + 2], c3 = csr[i + 3];
            float2 v0 = gsl2[(size_t)c0 * 4 + f2];
            float2 v1 = gsl2[(size_t)c1 * 4 + f2];
            float2 v2 = gsl2[(size_t)c2 * 4 + f2];
            float2 v3 = gsl2[(size_t)c3 * 4 + f2];
            ax += v0.x + v1.x; ay += v0.y + v1.y;
            bx += v2.x + v3.x; by += v2.y + v3.y;
        }
        for (; i < s1; ++i) {
            float2 v = gsl2[(size_t)csr[i] * 4 + f2];
            ax += v.x; ay += v.y;
        }
        float2 o;
        o.x = (ax + bx) * inv;
        o.y = (ay + by) * inv;
        asl2[(size_t)n * 4 + f2] = o;
    }
}

// ---------------- SAGE linear (+ReLU): one thread per (node, output-half) ----------------
// blockIdx.y = h selects output rows h*32..h*32+31. Doubles the wave count
// (R17: 391 blocks -> 6 waves/CU, occupancy 16%, VALU 18% — grid-starved).
// Inputs re-read by the second half hit L2. acc[32]/thread.
__global__ void __launch_bounds__(256) k_lin3(const float* __restrict__ aggT,
        const float* __restrict__ rootT,
        const float* __restrict__ Wl, const float* __restrict__ bl,
        const float* __restrict__ Wr, float* __restrict__ outT) {
    int tid = blockIdx.x * 256 + threadIdx.x;
    int h = blockIdx.y;                // 0 or 1
    int n = tid < NN ? tid : NN - 1;   // clamp; store guarded

    float acc[32];
#pragma unroll
    for (int d = 0; d < 32; ++d) acc[d] = bl[h * 32 + d];

    const float4* ap = (const float4*)(aggT + (size_t)n * 8);
    const float4* rp = (const float4*)(rootT + (size_t)n * 8);
    const size_t cstep = (size_t)NN * 2;   // chunk stride in float4s
    const float* WlH = Wl + h * 32 * 64;
    const float* WrH = Wr + h * 32 * 64;

    float4 a0 = ap[0], a1 = ap[1], r0 = rp[0], r1 = rp[1];
    for (int c = 0; c < 8; ++c) {
        float av[8] = {a0.x, a0.y, a0.z, a0.w, a1.x, a1.y, a1.z, a1.w};
        float rv[8] = {r0.x, r0.y, r0.z, r0.w, r1.x, r1.y, r1.z, r1.w};
        if (c < 7) {
            size_t off = (size_t)(c + 1) * cstep;
            a0 = ap[off]; a1 = ap[off + 1];
            r0 = rp[off]; r1 = rp[off + 1];
        }
        const float* wlc = WlH + c * 8;   // local row d, cols c*8..c*8+7
        const float* wrc = WrH + c * 8;
#pragma unroll
        for (int d = 0; d < 32; ++d) {
#pragma unroll
            for (int k = 0; k < 8; ++k) {
                acc[d] += av[k] * wlc[d * 64 + k];
                acc[d] += rv[k] * wrc[d * 64 + k];
            }
        }
    }

    if (tid < NN) {
#pragma unroll
        for (int c2 = 0; c2 < 4; ++c2) {
            int c = h * 4 + c2;
            float4 o0, o1;
            o0.x = fmaxf(acc[c2 * 8 + 0], 0.f); o0.y = fmaxf(acc[c2 * 8 + 1], 0.f);
            o0.z = fmaxf(acc[c2 * 8 + 2], 0.f); o0.w = fmaxf(acc[c2 * 8 + 3], 0.f);
            o1.x = fmaxf(acc[c2 * 8 + 4], 0.f); o1.y = fmaxf(acc[c2 * 8 + 5], 0.f);
            o1.z = fmaxf(acc[c2 * 8 + 6], 0.f); o1.w = fmaxf(acc[c2 * 8 + 7], 0.f);
            float4* op = (float4*)(outT + (size_t)c * NN * 8 + (size_t)n * 8);
            op[0] = o0; op[1] = o1;
        }
    }
}

// ---------------- per-graph mean-pool from h2 slabs (batch sorted) ----------------
__global__ void __launch_bounds__(256) k_pools(const float* __restrict__ hT,
        const int* __restrict__ batch, float* __restrict__ pooled) {
    int lane = threadIdx.x & 63;
    int wave = threadIdx.x >> 6;
    int n0 = blockIdx.x * 256 + wave * 64;
    if (n0 >= NN) return;
    const float* base = hT + (size_t)(lane >> 3) * NN * 8 + (lane & 7);
    int gcur = batch[n0];
    float rsum = 0.f;
    int nend = min(n0 + 64, NN);
    for (int n = n0; n < nend; ++n) {
        float v = base[(size_t)n * 8];
        int g = batch[n];
        if (g != gcur) {
            atomAddF(&pooled[(size_t)gcur * D + lane], rsum);
            rsum = 0.f; gcur = g;
        }
        rsum += v;
    }
    atomAddF(&pooled[(size_t)gcur * D + lane], rsum);
}

// ---------------- readout ----------------
__global__ void __launch_bounds__(256) k_bounds(const int* __restrict__ batch, int* __restrict__ gs) {
    int n = blockIdx.x * blockDim.x + threadIdx.x;
    if (n >= NN) return;
    int b = batch[n];
    if (n == 0) {
        for (int g = 0; g <= b; ++g) gs[g] = 0;
    } else {
        int bp = batch[n - 1];
        for (int g = bp + 1; g <= b; ++g) gs[g] = n;
    }
    if (n == NN - 1) {
        for (int g = b + 1; g <= NG; ++g) gs[g] = NN;
    }
}

__global__ void __launch_bounds__(256) k_out(const int* __restrict__ gs,
        const float* __restrict__ pooled, const float* __restrict__ Wout,
        const float* __restrict__ bout, float* __restrict__ out) {
    int lane = threadIdx.x & 63;
    int wave = threadIdx.x >> 6;
    int g = blockIdx.x * 4 + wave;       // 512 blocks
    int s0 = gs[g], s1 = gs[g + 1];
    float p = pooled[(size_t)g * D + lane] / (float)max(s1 - s0, 1);
    float c0 = p * Wout[lane];
    float c1 = p * Wout[D + lane];
#pragma unroll
    for (int off = 32; off > 0; off >>= 1) {
        c0 += __shfl_down(c0, off, 64);
        c1 += __shfl_down(c1, off, 64);
    }
    if (lane == 0) {
        out[g * C + 0] = c0 + bout[0];
        out[g * C + 1] = c1 + bout[1];
    }
}

extern "C" void kernel_launch(void* const* d_in, const int* in_sizes, int n_in,
                              void* d_out, int out_size, void* d_ws, size_t ws_size,
                              hipStream_t stream) {
    const int*   x     = (const int*)d_in[0];
    const int*   src   = (const int*)d_in[1];
    const int*   dst   = src + NE;
    const int*   batch = (const int*)d_in[2];
    const float* emb   = (const float*)d_in[3];
    const float* W1l   = (const float*)d_in[4];
    const float* b1l   = (const float*)d_in[5];
    const float* W1r   = (const float*)d_in[6];
    const float* W2l   = (const float*)d_in[7];
    const float* b2l   = (const float*)d_in[8];
    const float* W2r   = (const float*)d_in[9];
    const float* Wout  = (const float*)d_in[10];
    const float* bout  = (const float*)d_in[11];
    float* out = (float*)d_out;

    float* T0     = (float*)d_ws;                 // NN*64  h0 -> h1 slabs (in place)
    float* TA     = T0 + (size_t)NN * 64;         // NN*64  agg slabs -> h2 slabs (in place)
    float* pooled = TA + (size_t)NN * 64;         // NG*64
    int* bcur   = (int*)(pooled + (size_t)NG * 64);  // NBK  (contiguous w/ pooled for memset)
    int* bstart = bcur + NBK;                        // NBK+1
    int* startA = bstart + NBK + 1;                  // NN+1
    int* gs     = startA + NN + 1;                   // NG+1
    int* csr    = gs + NG + 1;                       // NE
    unsigned* barr = (unsigned*)(csr + NE);          // NBK*SLOT (~5.6 MB)

    hipMemsetAsync(pooled, 0, ((size_t)NG * 64 + NBK) * sizeof(float), stream);

    k_bucket<<<192, 256, 0, stream>>>(src, dst, bcur, barr);
    k_bscan <<<1, 256, 0, stream>>>(bcur, bstart, startA);
    k_sortb <<<NBK, 256, 0, stream>>>(bcur, bstart, barr, startA, csr);
    k_bounds<<<(NN + 255) / 256, 256, 0, stream>>>(batch, gs);
    k_embedT<<<(NN * 64 + 255) / 256, 256, 0, stream>>>(x, emb, T0);

    dim3 linGrid((NN + 255) / 256, 2);
    // ---- layer 1 ----
    k_agg2<<<((NN + 127) / 128) * 8, 256, 0, stream>>>(startA, csr, T0, TA);
    k_lin3<<<linGrid, 256, 0, stream>>>(TA, T0, W1l, b1l, W1r, T0);
    // ---- layer 2 ----
    k_agg2<<<((NN + 127) / 128) * 8, 256, 0, stream>>>(startA, csr, T0, TA);
    k_lin3<<<linGrid, 256, 0, stream>>>(TA, T0, W2l, b2l, W2r, TA);

    // ---- readout ----
    k_pools<<<(NN + 255) / 256, 256, 0, stream>>>(TA, batch, pooled);
    k_out<<<NG / 4, 256, 0, stream>>>(gs, pooled, Wout, bout, out);
}

// Round 19
// 356.711 us; speedup vs baseline: 1.1654x; 1.0463x over previous
//
#include <hip/hip_runtime.h>

#define NN 100000
#define NE 1200000
#define NG 2048
#define VOCAB 10000
#define D 64
#define C 2

#define NBK 196      // coarse buckets of 512 nodes (dst >> 9)
#define BSH 9
#define SLOT 7168    // per-bucket slot stride; mean 6144, sd 78 -> +13 sigma

__device__ __forceinline__ int atomAddI(int* p, int v) {
    return __hip_atomic_fetch_add(p, v, __ATOMIC_RELAXED, __HIP_MEMORY_SCOPE_AGENT);
}
__device__ __forceinline__ void atomAddF(float* p, float v) {
    __hip_atomic_fetch_add(p, v, __ATOMIC_RELAXED, __HIP_MEMORY_SCOPE_AGENT);
}

// ---------------- phase A: coarse bucket scatter (packed src|dlow) ----------------
__global__ void __launch_bounds__(256) k_bucket(const int* __restrict__ src,
        const int* __restrict__ dst, int* __restrict__ bcur, unsigned* __restrict__ barr) {
    __shared__ int hcnt[NBK], hbase[NBK], hrank[NBK];
    int tid = threadIdx.x;
    if (tid < NBK) { hcnt[tid] = 0; hrank[tid] = 0; }
    __syncthreads();
    int per = (NE + gridDim.x - 1) / gridDim.x;
    int e0 = blockIdx.x * per, e1 = min(e0 + per, NE);
    for (int e = e0 + tid; e < e1; e += 256)
        atomicAdd(&hcnt[dst[e] >> BSH], 1);
    __syncthreads();
    if (tid < NBK) {
        int c = hcnt[tid];
        hbase[tid] = c ? atomAddI(&bcur[tid], c) : 0;
    }
    __syncthreads();
    for (int e = e0 + tid; e < e1; e += 256) {
        int d = dst[e], s = src[e];
        int b = d >> BSH;
        int r = atomicAdd(&hrank[b], 1);
        barr[(size_t)b * SLOT + hbase[b] + r] = ((unsigned)s << BSH) | (unsigned)(d & 511);
    }
}

// ---------------- bucket-count scan ----------------
__global__ void __launch_bounds__(256) k_bscan(const int* __restrict__ bcur,
        int* __restrict__ bstart, int* __restrict__ start) {
    __shared__ int sm[256];
    int t = threadIdx.x;
    int v0 = (t < NBK) ? bcur[t] : 0;
    sm[t] = v0;
    __syncthreads();
    for (int off = 1; off < 256; off <<= 1) {
        int v = (t >= off) ? sm[t - off] : 0;
        __syncthreads();
        sm[t] += v;
        __syncthreads();
    }
    if (t < NBK) bstart[t] = sm[t] - v0;
    if (t == 0) { bstart[NBK] = NE; start[NN] = NE; }
}

// ---------------- phase B: exact CSR within each bucket; also emits xcsr ----------------
__global__ void __launch_bounds__(256) k_sortb(const int* __restrict__ bcur,
        const int* __restrict__ bstart, const unsigned* __restrict__ barr,
        const int* __restrict__ x,
        int* __restrict__ start, int* __restrict__ csr, int* __restrict__ xcsr) {
    __shared__ int cnt[512], loc[512], sm[256];
    int t = threadIdx.x;
    int b = blockIdx.x;
    cnt[t] = 0; cnt[t + 256] = 0;
    __syncthreads();
    int count = bcur[b];
    int base  = bstart[b];
    const unsigned* bp = barr + (size_t)b * SLOT;
    for (int i = t; i < count; i += 256)
        atomicAdd(&cnt[bp[i] & 511], 1);
    __syncthreads();
    int c0 = cnt[2 * t], c1 = cnt[2 * t + 1];
    int s = c0 + c1;
    sm[t] = s;
    __syncthreads();
    for (int off = 1; off < 256; off <<= 1) {
        int v = (t >= off) ? sm[t - off] : 0;
        __syncthreads();
        sm[t] += v;
        __syncthreads();
    }
    int ex = sm[t] - s;
    loc[2 * t] = ex; loc[2 * t + 1] = ex + c0;
    int g0 = b << BSH;
    if (g0 + 2 * t < NN)     start[g0 + 2 * t]     = base + ex;
    if (g0 + 2 * t + 1 < NN) start[g0 + 2 * t + 1] = base + ex + c0;
    __syncthreads();
    for (int i = t; i < count; i += 256) {
        unsigned p = bp[i];
        int r = atomicAdd(&loc[p & 511], 1);
        int sn = (int)(p >> BSH);
        csr[base + r]  = sn;
        xcsr[base + r] = x[sn];     // fused vocab lookup for layer-1 gather
    }
}

// ---------------- chunked aggregate: float2 lanes; RS = row stride in float2 ----
// RS=4: gather slab gT[c][n][8] (layer 2). RS=32: gather emb rows directly
// (layer 1, idx = xcsr; emb is 2.56 MB -> L2-resident, per-chunk footprint
// ~1.3 MB). chunk-per-XCD swizzle: c = blockIdx.x & 7.
template<int RS>
__global__ void __launch_bounds__(256) k_agg2(const int* __restrict__ start,
        const int* __restrict__ idx, const float* __restrict__ gsrc,
        float* __restrict__ aggT) {
    int tid = threadIdx.x;
    int lane = tid & 63, wave = tid >> 6;
    int c  = blockIdx.x & 7;
    int nb = blockIdx.x >> 3;            // 0..781
    int f2 = lane & 3, nsub = lane >> 2; // nsub 0..15
    const float2* gsl2 = (const float2*)gsrc +
        (RS == 32 ? (size_t)(c * 4) : (size_t)c * NN * 4);
    float2* asl2 = (float2*)(aggT + (size_t)c * NN * 8);

    // streaming L2 warm of this chunk's gather source
    float pf = 0.f;
    {
        int i = nb * 256 + tid;
        int lim = (RS == 32) ? VOCAB * 16 : NN * 2;
        if (i < lim) {
            float4 v = ((const float4*)gsrc)[i];
            pf = v.x * 0.0f;
        }
    }

    int nbase = nb * 128 + wave * 16 + nsub;
    for (int b = 0; b < 2; ++b) {
        int n = nbase + b * 64;
        if (n >= NN) break;
        int s0 = start[n], s1 = start[n + 1];
        float inv = 1.0f / (float)max(s1 - s0, 1);
        float ax = pf, ay = 0.f, bx = 0.f, by = 0.f;
        int i = s0;
        for (; i + 4 <= s1; i += 4) {
            int c0 = idx[i], c1 = idx[i + 1], c2 = idx[i + 2], c3 = idx[i + 3];
            float2 v0 = gsl2[(size_t)c0 * RS + f2];
            float2 v1 = gsl2[(size_t)c1 * RS + f2];
            float2 v2 = gsl2[(size_t)c2 * RS + f2];
            float2 v3 = gsl2[(size_t)c3 * RS + f2];
            ax += v0.x + v1.x; ay += v0.y + v1.y;
            bx += v2.x + v3.x; by += v2.y + v3.y;
        }
        for (; i < s1; ++i) {
            float2 v = gsl2[(size_t)idx[i] * RS + f2];
            ax += v.x; ay += v.y;
        }
        float2 o;
        o.x = (ax + bx) * inv;
        o.y = (ay + by) * inv;
        asl2[(size_t)n * 4 + f2] = o;
    }
}

// ---------------- SAGE linear (+ReLU): one thread per (node, output-half) ----------------
// ROOTEMB: root row read directly from emb[x[n]] (layer 1, h0 never built).
template<bool ROOTEMB>
__global__ void __launch_bounds__(256) k_lin3(const float* __restrict__ aggT,
        const float* __restrict__ rootT, const int* __restrict__ x,
        const float4* __restrict__ emb4,
        const float* __restrict__ Wl, const float* __restrict__ bl,
        const float* __restrict__ Wr, float* __restrict__ outT) {
    int tid = blockIdx.x * 256 + threadIdx.x;
    int h = blockIdx.y;                // 0 or 1
    int n = tid < NN ? tid : NN - 1;   // clamp; store guarded

    float acc[32];
#pragma unroll
    for (int d = 0; d < 32; ++d) acc[d] = bl[h * 32 + d];

    const float4* ap = (const float4*)(aggT + (size_t)n * 8);
    const float4* rp;
    size_t rstep;
    if (ROOTEMB) {
        rp = emb4 + (size_t)x[n] * 16;   // contiguous 256B row
        rstep = 2;
    } else {
        rp = (const float4*)(rootT + (size_t)n * 8);
        rstep = (size_t)NN * 2;
    }
    const size_t cstep = (size_t)NN * 2;   // agg chunk stride in float4s
    const float* WlH = Wl + h * 32 * 64;
    const float* WrH = Wr + h * 32 * 64;

    float4 a0 = ap[0], a1 = ap[1], r0 = rp[0], r1 = rp[1];
    for (int c = 0; c < 8; ++c) {
        float av[8] = {a0.x, a0.y, a0.z, a0.w, a1.x, a1.y, a1.z, a1.w};
        float rv[8] = {r0.x, r0.y, r0.z, r0.w, r1.x, r1.y, r1.z, r1.w};
        if (c < 7) {
            size_t offA = (size_t)(c + 1) * cstep;
            size_t offR = (size_t)(c + 1) * rstep;
            a0 = ap[offA]; a1 = ap[offA + 1];
            r0 = rp[offR]; r1 = rp[offR + 1];
        }
        const float* wlc = WlH + c * 8;   // local row d, cols c*8..c*8+7
        const float* wrc = WrH + c * 8;
#pragma unroll
        for (int d = 0; d < 32; ++d) {
#pragma unroll
            for (int k = 0; k < 8; ++k) {
                acc[d] += av[k] * wlc[d * 64 + k];
                acc[d] += rv[k] * wrc[d * 64 + k];
            }
        }
    }

    if (tid < NN) {
#pragma unroll
        for (int c2 = 0; c2 < 4; ++c2) {
            int c = h * 4 + c2;
            float4 o0, o1;
            o0.x = fmaxf(acc[c2 * 8 + 0], 0.f); o0.y = fmaxf(acc[c2 * 8 + 1], 0.f);
            o0.z = fmaxf(acc[c2 * 8 + 2], 0.f); o0.w = fmaxf(acc[c2 * 8 + 3], 0.f);
            o1.x = fmaxf(acc[c2 * 8 + 4], 0.f); o1.y = fmaxf(acc[c2 * 8 + 5], 0.f);
            o1.z = fmaxf(acc[c2 * 8 + 6], 0.f); o1.w = fmaxf(acc[c2 * 8 + 7], 0.f);
            float4* op = (float4*)(outT + (size_t)c * NN * 8 + (size_t)n * 8);
            op[0] = o0; op[1] = o1;
        }
    }
}

// ---------------- per-graph mean-pool from h2 slabs (batch sorted) ----------------
__global__ void __launch_bounds__(256) k_pools(const float* __restrict__ hT,
        const int* __restrict__ batch, float* __restrict__ pooled) {
    int lane = threadIdx.x & 63;
    int wave = threadIdx.x >> 6;
    int n0 = blockIdx.x * 256 + wave * 64;
    if (n0 >= NN) return;
    const float* base = hT + (size_t)(lane >> 3) * NN * 8 + (lane & 7);
    int gcur = batch[n0];
    float rsum = 0.f;
    int nend = min(n0 + 64, NN);
    for (int n = n0; n < nend; ++n) {
        float v = base[(size_t)n * 8];
        int g = batch[n];
        if (g != gcur) {
            atomAddF(&pooled[(size_t)gcur * D + lane], rsum);
            rsum = 0.f; gcur = g;
        }
        rsum += v;
    }
    atomAddF(&pooled[(size_t)gcur * D + lane], rsum);
}

// ---------------- readout ----------------
__global__ void __launch_bounds__(256) k_bounds(const int* __restrict__ batch, int* __restrict__ gs) {
    int n = blockIdx.x * blockDim.x + threadIdx.x;
    if (n >= NN) return;
    int b = batch[n];
    if (n == 0) {
        for (int g = 0; g <= b; ++g) gs[g] = 0;
    } else {
        int bp = batch[n - 1];
        for (int g = bp + 1; g <= b; ++g) gs[g] = n;
    }
    if (n == NN - 1) {
        for (int g = b + 1; g <= NG; ++g) gs[g] = NN;
    }
}

__global__ void __launch_bounds__(256) k_out(const int* __restrict__ gs,
        const float* __restrict__ pooled, const float* __restrict__ Wout,
        const float* __restrict__ bout, float* __restrict__ out) {
    int lane = threadIdx.x & 63;
    int wave = threadIdx.x >> 6;
    int g = blockIdx.x * 4 + wave;       // 512 blocks
    int s0 = gs[g], s1 = gs[g + 1];
    float p = pooled[(size_t)g * D + lane] / (float)max(s1 - s0, 1);
    float c0 = p * Wout[lane];
    float c1 = p * Wout[D + lane];
#pragma unroll
    for (int off = 32; off > 0; off >>= 1) {
        c0 += __shfl_down(c0, off, 64);
        c1 += __shfl_down(c1, off, 64);
    }
    if (lane == 0) {
        out[g * C + 0] = c0 + bout[0];
        out[g * C + 1] = c1 + bout[1];
    }
}

extern "C" void kernel_launch(void* const* d_in, const int* in_sizes, int n_in,
                              void* d_out, int out_size, void* d_ws, size_t ws_size,
                              hipStream_t stream) {
    const int*   x     = (const int*)d_in[0];
    const int*   src   = (const int*)d_in[1];
    const int*   dst   = src + NE;
    const int*   batch = (const int*)d_in[2];
    const float* emb   = (const float*)d_in[3];
    const float* W1l   = (const float*)d_in[4];
    const float* b1l   = (const float*)d_in[5];
    const float* W1r   = (const float*)d_in[6];
    const float* W2l   = (const float*)d_in[7];
    const float* b2l   = (const float*)d_in[8];
    const float* W2r   = (const float*)d_in[9];
    const float* Wout  = (const float*)d_in[10];
    const float* bout  = (const float*)d_in[11];
    float* out = (float*)d_out;

    float* T0     = (float*)d_ws;                 // NN*64  h1 slabs
    float* TA     = T0 + (size_t)NN * 64;         // NN*64  agg slabs -> h2 slabs (in place)
    float* pooled = TA + (size_t)NN * 64;         // NG*64
    int* bcur   = (int*)(pooled + (size_t)NG * 64);  // NBK  (contiguous w/ pooled for memset)
    int* bstart = bcur + NBK;                        // NBK+1
    int* startA = bstart + NBK + 1;                  // NN+1
    int* gs     = startA + NN + 1;                   // NG+1
    int* csr    = gs + NG + 1;                       // NE
    int* xcsr   = csr + NE;                          // NE
    unsigned* barr = (unsigned*)(xcsr + NE);         // NBK*SLOT (~5.6 MB)

    hipMemsetAsync(pooled, 0, ((size_t)NG * 64 + NBK) * sizeof(float), stream);

    k_bucket<<<192, 256, 0, stream>>>(src, dst, bcur, barr);
    k_bscan <<<1, 256, 0, stream>>>(bcur, bstart, startA);
    k_sortb <<<NBK, 256, 0, stream>>>(bcur, bstart, barr, x, startA, csr, xcsr);
    k_bounds<<<(NN + 255) / 256, 256, 0, stream>>>(batch, gs);

    dim3 linGrid((NN + 255) / 256, 2);
    int aggGrid = ((NN + 127) / 128) * 8;
    // ---- layer 1: gather straight from emb via xcsr; root from emb[x[n]] ----
    k_agg2<32><<<aggGrid, 256, 0, stream>>>(startA, xcsr, emb, TA);
    k_lin3<true><<<linGrid, 256, 0, stream>>>(TA, nullptr, x, (const float4*)emb,
                                              W1l, b1l, W1r, T0);
    // ---- layer 2 ----
    k_agg2<4><<<aggGrid, 256, 0, stream>>>(startA, csr, T0, TA);
    k_lin3<false><<<linGrid, 256, 0, stream>>>(TA, T0, x, (const float4*)emb,
                                               W2l, b2l, W2r, TA);

    // ---- readout ----
    k_pools<<<(NN + 255) / 256, 256, 0, stream>>>(TA, batch, pooled);
    k_out<<<NG / 4, 256, 0, stream>>>(gs, pooled, Wout, bout, out);
}

// Round 20
// 354.696 us; speedup vs baseline: 1.1720x; 1.0057x over previous
//
#include <hip/hip_runtime.h>

#define NN 100000
#define NE 1200000
#define NG 2048
#define VOCAB 10000
#define D 64
#define C 2

#define NBK 196      // coarse buckets of 512 nodes (dst >> 9)
#define BSH 9
#define SLOT 7168    // per-bucket slot stride; mean 6144, sd 78 -> +13 sigma

__device__ __forceinline__ int atomAddI(int* p, int v) {
    return __hip_atomic_fetch_add(p, v, __ATOMIC_RELAXED, __HIP_MEMORY_SCOPE_AGENT);
}
__device__ __forceinline__ void atomAddF(float* p, float v) {
    __hip_atomic_fetch_add(p, v, __ATOMIC_RELAXED, __HIP_MEMORY_SCOPE_AGENT);
}

// ---------------- phase A: coarse bucket scatter (packed src|dlow) ----------------
__global__ void __launch_bounds__(256) k_bucket(const int* __restrict__ src,
        const int* __restrict__ dst, int* __restrict__ bcur, unsigned* __restrict__ barr) {
    __shared__ int hcnt[NBK], hbase[NBK], hrank[NBK];
    int tid = threadIdx.x;
    if (tid < NBK) { hcnt[tid] = 0; hrank[tid] = 0; }
    __syncthreads();
    int per = (NE + gridDim.x - 1) / gridDim.x;
    int e0 = blockIdx.x * per, e1 = min(e0 + per, NE);
    for (int e = e0 + tid; e < e1; e += 256)
        atomicAdd(&hcnt[dst[e] >> BSH], 1);
    __syncthreads();
    if (tid < NBK) {
        int c = hcnt[tid];
        hbase[tid] = c ? atomAddI(&bcur[tid], c) : 0;
    }
    __syncthreads();
    for (int e = e0 + tid; e < e1; e += 256) {
        int d = dst[e], s = src[e];
        int b = d >> BSH;
        int r = atomicAdd(&hrank[b], 1);
        barr[(size_t)b * SLOT + hbase[b] + r] = ((unsigned)s << BSH) | (unsigned)(d & 511);
    }
}

// ---------------- bucket-count scan ----------------
__global__ void __launch_bounds__(256) k_bscan(const int* __restrict__ bcur,
        int* __restrict__ bstart, int* __restrict__ start) {
    __shared__ int sm[256];
    int t = threadIdx.x;
    int v0 = (t < NBK) ? bcur[t] : 0;
    sm[t] = v0;
    __syncthreads();
    for (int off = 1; off < 256; off <<= 1) {
        int v = (t >= off) ? sm[t - off] : 0;
        __syncthreads();
        sm[t] += v;
        __syncthreads();
    }
    if (t < NBK) bstart[t] = sm[t] - v0;
    if (t == 0) { bstart[NBK] = NE; start[NN] = NE; }
}

// ---------------- phase B: exact CSR within each bucket; also emits u16 xcsr ----------------
__global__ void __launch_bounds__(256) k_sortb(const int* __restrict__ bcur,
        const int* __restrict__ bstart, const unsigned* __restrict__ barr,
        const int* __restrict__ x,
        int* __restrict__ start, int* __restrict__ csr, unsigned short* __restrict__ xcsr) {
    __shared__ int cnt[512], loc[512], sm[256];
    int t = threadIdx.x;
    int b = blockIdx.x;
    cnt[t] = 0; cnt[t + 256] = 0;
    __syncthreads();
    int count = bcur[b];
    int base  = bstart[b];
    const unsigned* bp = barr + (size_t)b * SLOT;
    for (int i = t; i < count; i += 256)
        atomicAdd(&cnt[bp[i] & 511], 1);
    __syncthreads();
    int c0 = cnt[2 * t], c1 = cnt[2 * t + 1];
    int s = c0 + c1;
    sm[t] = s;
    __syncthreads();
    for (int off = 1; off < 256; off <<= 1) {
        int v = (t >= off) ? sm[t - off] : 0;
        __syncthreads();
        sm[t] += v;
        __syncthreads();
    }
    int ex = sm[t] - s;
    loc[2 * t] = ex; loc[2 * t + 1] = ex + c0;
    int g0 = b << BSH;
    if (g0 + 2 * t < NN)     start[g0 + 2 * t]     = base + ex;
    if (g0 + 2 * t + 1 < NN) start[g0 + 2 * t + 1] = base + ex + c0;
    __syncthreads();
    for (int i = t; i < count; i += 256) {
        unsigned p = bp[i];
        int r = atomicAdd(&loc[p & 511], 1);
        int sn = (int)(p >> BSH);
        csr[base + r]  = sn;
        xcsr[base + r] = (unsigned short)x[sn];   // VOCAB=10000 < 65536
    }
}

// ---------------- chunked aggregate: float2 lanes; templated idx type + row stride ----
// RS=4 + int idx: gather slab gT[c][n][8] (layer 2).
// RS=32 + ushort idx: gather emb rows directly (layer 1; emb L2-resident,
// idx stream halved to 2.4 MB). chunk-per-XCD swizzle: c = blockIdx.x & 7.
template<int RS, typename IDX>
__global__ void __launch_bounds__(256) k_agg2(const int* __restrict__ start,
        const IDX* __restrict__ idx, const float* __restrict__ gsrc,
        float* __restrict__ aggT) {
    int tid = threadIdx.x;
    int lane = tid & 63, wave = tid >> 6;
    int c  = blockIdx.x & 7;
    int nb = blockIdx.x >> 3;            // 0..781
    int f2 = lane & 3, nsub = lane >> 2; // nsub 0..15
    const float2* gsl2 = (const float2*)gsrc +
        (RS == 32 ? (size_t)(c * 4) : (size_t)c * NN * 4);
    float2* asl2 = (float2*)(aggT + (size_t)c * NN * 8);

    // streaming L2 warm of this chunk's gather source
    float pf = 0.f;
    {
        int i = nb * 256 + tid;
        int lim = (RS == 32) ? VOCAB * 16 : NN * 2;
        if (i < lim) {
            float4 v = ((const float4*)gsrc)[i];
            pf = v.x * 0.0f;
        }
    }

    int nbase = nb * 128 + wave * 16 + nsub;
    for (int b = 0; b < 2; ++b) {
        int n = nbase + b * 64;
        if (n >= NN) break;
        int s0 = start[n], s1 = start[n + 1];
        float inv = 1.0f / (float)max(s1 - s0, 1);
        float ax = pf, ay = 0.f, bx = 0.f, by = 0.f;
        int i = s0;
        for (; i + 4 <= s1; i += 4) {
            int c0 = idx[i], c1 = idx[i + 1], c2 = idx[i + 2], c3 = idx[i + 3];
            float2 v0 = gsl2[(size_t)c0 * RS + f2];
            float2 v1 = gsl2[(size_t)c1 * RS + f2];
            float2 v2 = gsl2[(size_t)c2 * RS + f2];
            float2 v3 = gsl2[(size_t)c3 * RS + f2];
            ax += v0.x + v1.x; ay += v0.y + v1.y;
            bx += v2.x + v3.x; by += v2.y + v3.y;
        }
        for (; i < s1; ++i) {
            float2 v = gsl2[(size_t)idx[i] * RS + f2];
            ax += v.x; ay += v.y;
        }
        float2 o;
        o.x = (ax + bx) * inv;
        o.y = (ay + by) * inv;
        asl2[(size_t)n * 4 + f2] = o;
    }
}

// ---------------- SAGE linear (+ReLU): one thread per (node, output-quarter) ----------------
// blockIdx.y = h in [0,4): output rows h*16..h*16+15. 1564 blocks ≈ 24 waves/CU.
// ROOTEMB: root row read directly from emb[x[n]] (layer 1, h0 never built).
template<bool ROOTEMB>
__global__ void __launch_bounds__(256) k_lin3(const float* __restrict__ aggT,
        const float* __restrict__ rootT, const int* __restrict__ x,
        const float4* __restrict__ emb4,
        const float* __restrict__ Wl, const float* __restrict__ bl,
        const float* __restrict__ Wr, float* __restrict__ outT) {
    int tid = blockIdx.x * 256 + threadIdx.x;
    int h = blockIdx.y;                // 0..3
    int n = tid < NN ? tid : NN - 1;   // clamp; store guarded

    float acc[16];
#pragma unroll
    for (int d = 0; d < 16; ++d) acc[d] = bl[h * 16 + d];

    const float4* ap = (const float4*)(aggT + (size_t)n * 8);
    const float4* rp;
    size_t rstep;
    if (ROOTEMB) {
        rp = emb4 + (size_t)x[n] * 16;   // contiguous 256B row
        rstep = 2;
    } else {
        rp = (const float4*)(rootT + (size_t)n * 8);
        rstep = (size_t)NN * 2;
    }
    const size_t cstep = (size_t)NN * 2;   // agg chunk stride in float4s
    const float* WlH = Wl + h * 16 * 64;
    const float* WrH = Wr + h * 16 * 64;

    float4 a0 = ap[0], a1 = ap[1], r0 = rp[0], r1 = rp[1];
    for (int c = 0; c < 8; ++c) {
        float av[8] = {a0.x, a0.y, a0.z, a0.w, a1.x, a1.y, a1.z, a1.w};
        float rv[8] = {r0.x, r0.y, r0.z, r0.w, r1.x, r1.y, r1.z, r1.w};
        if (c < 7) {
            size_t offA = (size_t)(c + 1) * cstep;
            size_t offR = (size_t)(c + 1) * rstep;
            a0 = ap[offA]; a1 = ap[offA + 1];
            r0 = rp[offR]; r1 = rp[offR + 1];
        }
        const float* wlc = WlH + c * 8;   // local row d, cols c*8..c*8+7
        const float* wrc = WrH + c * 8;
#pragma unroll
        for (int d = 0; d < 16; ++d) {
#pragma unroll
            for (int k = 0; k < 8; ++k) {
                acc[d] += av[k] * wlc[d * 64 + k];
                acc[d] += rv[k] * wrc[d * 64 + k];
            }
        }
    }

    if (tid < NN) {
#pragma unroll
        for (int c2 = 0; c2 < 2; ++c2) {
            int c = h * 2 + c2;
            float4 o0, o1;
            o0.x = fmaxf(acc[c2 * 8 + 0], 0.f); o0.y = fmaxf(acc[c2 * 8 + 1], 0.f);
            o0.z = fmaxf(acc[c2 * 8 + 2], 0.f); o0.w = fmaxf(acc[c2 * 8 + 3], 0.f);
            o1.x = fmaxf(acc[c2 * 8 + 4], 0.f); o1.y = fmaxf(acc[c2 * 8 + 5], 0.f);
            o1.z = fmaxf(acc[c2 * 8 + 6], 0.f); o1.w = fmaxf(acc[c2 * 8 + 7], 0.f);
            float4* op = (float4*)(outT + (size_t)c * NN * 8 + (size_t)n * 8);
            op[0] = o0; op[1] = o1;
        }
    }
}

// ---------------- per-graph mean-pool from h2 slabs (batch sorted) ----------------
__global__ void __launch_bounds__(256) k_pools(const float* __restrict__ hT,
        const int* __restrict__ batch, float* __restrict__ pooled) {
    int lane = threadIdx.x & 63;
    int wave = threadIdx.x >> 6;
    int n0 = blockIdx.x * 256 + wave * 64;
    if (n0 >= NN) return;
    const float* base = hT + (size_t)(lane >> 3) * NN * 8 + (lane & 7);
    int gcur = batch[n0];
    float rsum = 0.f;
    int nend = min(n0 + 64, NN);
    for (int n = n0; n < nend; ++n) {
        float v = base[(size_t)n * 8];
        int g = batch[n];
        if (g != gcur) {
            atomAddF(&pooled[(size_t)gcur * D + lane], rsum);
            rsum = 0.f; gcur = g;
        }
        rsum += v;
    }
    atomAddF(&pooled[(size_t)gcur * D + lane], rsum);
}

// ---------------- readout ----------------
__global__ void __launch_bounds__(256) k_bounds(const int* __restrict__ batch, int* __restrict__ gs) {
    int n = blockIdx.x * blockDim.x + threadIdx.x;
    if (n >= NN) return;
    int b = batch[n];
    if (n == 0) {
        for (int g = 0; g <= b; ++g) gs[g] = 0;
    } else {
        int bp = batch[n - 1];
        for (int g = bp + 1; g <= b; ++g) gs[g] = n;
    }
    if (n == NN - 1) {
        for (int g = b + 1; g <= NG; ++g) gs[g] = NN;
    }
}

__global__ void __launch_bounds__(256) k_out(const int* __restrict__ gs,
        const float* __restrict__ pooled, const float* __restrict__ Wout,
        const float* __restrict__ bout, float* __restrict__ out) {
    int lane = threadIdx.x & 63;
    int wave = threadIdx.x >> 6;
    int g = blockIdx.x * 4 + wave;       // 512 blocks
    int s0 = gs[g], s1 = gs[g + 1];
    float p = pooled[(size_t)g * D + lane] / (float)max(s1 - s0, 1);
    float c0 = p * Wout[lane];
    float c1 = p * Wout[D + lane];
#pragma unroll
    for (int off = 32; off > 0; off >>= 1) {
        c0 += __shfl_down(c0, off, 64);
        c1 += __shfl_down(c1, off, 64);
    }
    if (lane == 0) {
        out[g * C + 0] = c0 + bout[0];
        out[g * C + 1] = c1 + bout[1];
    }
}

extern "C" void kernel_launch(void* const* d_in, const int* in_sizes, int n_in,
                              void* d_out, int out_size, void* d_ws, size_t ws_size,
                              hipStream_t stream) {
    const int*   x     = (const int*)d_in[0];
    const int*   src   = (const int*)d_in[1];
    const int*   dst   = src + NE;
    const int*   batch = (const int*)d_in[2];
    const float* emb   = (const float*)d_in[3];
    const float* W1l   = (const float*)d_in[4];
    const float* b1l   = (const float*)d_in[5];
    const float* W1r   = (const float*)d_in[6];
    const float* W2l   = (const float*)d_in[7];
    const float* b2l   = (const float*)d_in[8];
    const float* W2r   = (const float*)d_in[9];
    const float* Wout  = (const float*)d_in[10];
    const float* bout  = (const float*)d_in[11];
    float* out = (float*)d_out;

    float* T0     = (float*)d_ws;                 // NN*64  h1 slabs
    float* TA     = T0 + (size_t)NN * 64;         // NN*64  agg slabs -> h2 slabs (in place)
    float* pooled = TA + (size_t)NN * 64;         // NG*64
    int* bcur   = (int*)(pooled + (size_t)NG * 64);  // NBK  (contiguous w/ pooled for memset)
    int* bstart = bcur + NBK;                        // NBK+1
    int* startA = bstart + NBK + 1;                  // NN+1
    int* gs     = startA + NN + 1;                   // NG+1
    int* csr    = gs + NG + 1;                       // NE
    unsigned short* xcsr = (unsigned short*)(csr + NE);  // NE u16
    unsigned* barr = (unsigned*)(xcsr + NE);         // NBK*SLOT (~5.6 MB)

    hipMemsetAsync(pooled, 0, ((size_t)NG * 64 + NBK) * sizeof(float), stream);

    k_bucket<<<192, 256, 0, stream>>>(src, dst, bcur, barr);
    k_bscan <<<1, 256, 0, stream>>>(bcur, bstart, startA);
    k_sortb <<<NBK, 256, 0, stream>>>(bcur, bstart, barr, x, startA, csr, xcsr);
    k_bounds<<<(NN + 255) / 256, 256, 0, stream>>>(batch, gs);

    dim3 linGrid((NN + 255) / 256, 4);
    int aggGrid = ((NN + 127) / 128) * 8;
    // ---- layer 1: gather straight from emb via u16 xcsr; root from emb[x[n]] ----
    k_agg2<32, unsigned short><<<aggGrid, 256, 0, stream>>>(startA, xcsr, emb, TA);
    k_lin3<true><<<linGrid, 256, 0, stream>>>(TA, nullptr, x, (const float4*)emb,
                                              W1l, b1l, W1r, T0);
    // ---- layer 2 ----
    k_agg2<4, int><<<aggGrid, 256, 0, stream>>>(startA, csr, T0, TA);
    k_lin3<false><<<linGrid, 256, 0, stream>>>(TA, T0, x, (const float4*)emb,
                                               W2l, b2l, W2r, TA);

    // ---- readout ----
    k_pools<<<(NN + 255) / 256, 256, 0, stream>>>(TA, batch, pooled);
    k_out<<<NG / 4, 256, 0, stream>>>(gs, pooled, Wout, bout, out);
}